// Round 1
// baseline (1115.697 us; speedup 1.0000x reference)
//
#include <hip/hip_runtime.h>

// VecLeadingZeroDetector108: X [n_rows, 108] float32 bits (exact 0.0/1.0),
// out [n_rows, 7] float32 = binary (MSB-first) index of first set bit, or
// 108 = 1101100b if the row is all zero.
//
// Strategy v2: fully-coalesced, data-independent stream.
//  - Block of 256 threads owns 256 contiguous rows = 6912 float4.
//  - Phase 1: lane t loads float4 (t + 256*it), it=0..26 — perfect 16B/lane
//    coalescing, 27 independent loads the compiler can pipeline. Each float4
//    reduces to a 16-bit key = bit-position-in-row of its first nonzero
//    element (0xFFFF if none), stored to LDS keys[row][chunk] (row-major,
//    padded to 28 so each row is 56B, 8B-aligned for uint2 reads).
//  - Phase 2: thread t min-reduces row t's 28 keys (7x ds_read_b64),
//    min key == first set bit position; 0xFFFF everywhere == all-zero -> 108.
//  - One __syncthreads, 14.3KB LDS (8 blocks/CU fits), no data-dependent
//    control flow -> DRAM sees a pure sequential stream.
// Inputs are exactly 0.0f/1.0f so `!= 0.0f` reproduces the reference's
// soft-gate logic bit-exactly.

#define LZD_NBITS 108
#define LZD_NOUT 7
#define RPB 256            // rows per block (== blockDim.x)
#define F4R 27             // float4 per row (108 floats)
#define F4B (RPB * F4R)    // 6912 float4 per block
#define KPAD 28            // padded keys per row (56B, 8B-aligned)

static __device__ __forceinline__ unsigned umin_(unsigned a, unsigned b) {
    return a < b ? a : b;
}

__global__ __launch_bounds__(256) void lzd108_kernel(const float* __restrict__ X,
                                                     float* __restrict__ out,
                                                     int n_rows) {
    __shared__ unsigned short keys[RPB][KPAD];
    const int tid = threadIdx.x;
    const size_t row0 = (size_t)blockIdx.x * RPB;
    const float4* __restrict__ p =
        reinterpret_cast<const float4*>(X) + row0 * F4R;

    // pad slot; written before the barrier, never touched by phase 1
    keys[tid][F4R] = (unsigned short)0xFFFFu;

    const size_t nf4_rem = ((size_t)n_rows - row0) * F4R;

    if (nf4_rem >= (size_t)F4B) {
        // full block: unguarded, fully unrolled
        #pragma unroll
        for (int it = 0; it < F4B / RPB; ++it) {
            const int i = tid + it * RPB;
            const float4 v = p[i];
            const int r = i / F4R;
            const int c = i - r * F4R;
            const unsigned sub = (v.x != 0.0f) ? 0u
                               : (v.y != 0.0f) ? 1u
                               : (v.z != 0.0f) ? 2u
                               : (v.w != 0.0f) ? 3u : 4u;
            keys[r][c] = (sub == 4u) ? (unsigned short)0xFFFFu
                                     : (unsigned short)(4u * (unsigned)c + sub);
        }
    } else {
        // tail block: nf4_rem is a multiple of 27, rows < n_rows fully covered
        const int nf4 = (int)nf4_rem;
        #pragma unroll 1
        for (int i = tid; i < nf4; i += RPB) {
            const float4 v = p[i];
            const int r = i / F4R;
            const int c = i - r * F4R;
            const unsigned sub = (v.x != 0.0f) ? 0u
                               : (v.y != 0.0f) ? 1u
                               : (v.z != 0.0f) ? 2u
                               : (v.w != 0.0f) ? 3u : 4u;
            keys[r][c] = (sub == 4u) ? (unsigned short)0xFFFFu
                                     : (unsigned short)(4u * (unsigned)c + sub);
        }
    }
    __syncthreads();

    const size_t row = row0 + (size_t)tid;
    if (row < (size_t)n_rows) {
        // 28 keys = 7 x uint2 (8B-aligned: row stride 56B)
        const uint2* kp = reinterpret_cast<const uint2*>(&keys[tid][0]);
        unsigned m = 0xFFFFu;
        #pragma unroll
        for (int j = 0; j < 7; ++j) {
            const uint2 u = kp[j];
            m = umin_(m, umin_(umin_(u.x & 0xFFFFu, u.x >> 16),
                               umin_(u.y & 0xFFFFu, u.y >> 16)));
        }
        const unsigned idx = (m > 107u) ? (unsigned)LZD_NBITS : m;
        float* o = out + row * LZD_NOUT;
        o[0] = (float)((idx >> 6) & 1u);
        o[1] = (float)((idx >> 5) & 1u);
        o[2] = (float)((idx >> 4) & 1u);
        o[3] = (float)((idx >> 3) & 1u);
        o[4] = (float)((idx >> 2) & 1u);
        o[5] = (float)((idx >> 1) & 1u);
        o[6] = (float)(idx & 1u);
    }
}

extern "C" void kernel_launch(void* const* d_in, const int* in_sizes, int n_in,
                              void* d_out, int out_size, void* d_ws, size_t ws_size,
                              hipStream_t stream) {
    const float* X = (const float*)d_in[0];
    float* out = (float*)d_out;
    int n_rows = in_sizes[0] / LZD_NBITS;
    int block = 256;
    int grid = (n_rows + RPB - 1) / RPB;
    lzd108_kernel<<<grid, block, 0, stream>>>(X, out, n_rows);
}

// Round 2
// 1087.754 us; speedup vs baseline: 1.0257x; 1.0257x over previous
//
#include <hip/hip_runtime.h>

// VecLeadingZeroDetector108: X [n_rows, 108] float32 bits (exact 0.0/1.0),
// out [n_rows, 7] float32 = binary (MSB-first) index of first set bit, or
// 108 = 1101100b if the row is all zero.
//
// Strategy v3: roofline-tuned data-independent stream.
//  - Block = 256 threads = 256 contiguous rows = 6912 float4.
//  - Phase 1: 3 groups of 9 coalesced uint4 loads per thread (bounded unroll:
//    ~40 load VGPRs, 9 loads in flight per wave). Each float4 -> 16-bit key =
//    first-set bit position in row (0xFFFF if none) via integer nonzero tests
//    (inputs are exactly 0.0f/1.0f so bit-pattern != 0 is exact).
//    keys[row][chunk] in LDS, row stride 56B (<=2-way bank aliasing, free).
//  - Phase 2: thread t min-reduces row t's 28 keys (7x ds_read_b64,
//    v_min3-friendly); min key == first set bit; all-0xFFFF == all-zero -> 108.
//  - Phase 3: outputs staged in LDS (stride-7, <=2-way) then written back as
//    fully-coalesced dword stores (full-line writes, no partial sectors).
//  - Two barriers, 21.5KB LDS, zero data-dependent control flow.

#define LZD_NBITS 108
#define LZD_NOUT  7
#define RPB  256           // rows per block (== blockDim.x)
#define F4R  27            // float4 per row
#define F4B  (RPB * F4R)   // 6912 float4 per block
#define KPAD 28            // padded keys per row (56B, 8B-aligned)
#define GRP  9             // loads in flight per thread per group

__global__ __launch_bounds__(256) void lzd108_kernel(const float* __restrict__ X,
                                                     float* __restrict__ out,
                                                     int n_rows) {
    __shared__ unsigned short keys[RPB][KPAD];     // 14336 B
    __shared__ float outs[RPB * LZD_NOUT];         //  7168 B

    const int tid = threadIdx.x;
    const size_t row0 = (size_t)blockIdx.x * RPB;
    const uint4* __restrict__ p =
        reinterpret_cast<const uint4*>(X) + row0 * F4R;

    // pad slot (chunk 27) participates in the min-reduce; set once
    keys[tid][F4R] = (unsigned short)0xFFFFu;

    const size_t nf4_rem = ((size_t)n_rows - row0) * F4R;

    if (nf4_rem >= (size_t)F4B) {
        // full block
        #pragma unroll 1
        for (int g = 0; g < F4R / GRP; ++g) {
            uint4 v[GRP];
            #pragma unroll
            for (int u = 0; u < GRP; ++u)
                v[u] = p[tid + (g * GRP + u) * RPB];
            #pragma unroll
            for (int u = 0; u < GRP; ++u) {
                const int i = tid + (g * GRP + u) * RPB;
                const int r = i / F4R;
                const int c = i - r * F4R;
                const uint4 w = v[u];
                const unsigned sub = w.x ? 0u : w.y ? 1u : w.z ? 2u
                                   : w.w ? 3u : 4u;
                keys[r][c] = (sub == 4u)
                                 ? (unsigned short)0xFFFFu
                                 : (unsigned short)(4u * (unsigned)c + sub);
            }
        }
    } else {
        // tail block: nf4_rem is a multiple of 27; rows < n_rows fully covered
        const int nf4 = (int)nf4_rem;
        #pragma unroll 1
        for (int i = tid; i < nf4; i += RPB) {
            const uint4 w = p[i];
            const int r = i / F4R;
            const int c = i - r * F4R;
            const unsigned sub = w.x ? 0u : w.y ? 1u : w.z ? 2u
                               : w.w ? 3u : 4u;
            keys[r][c] = (sub == 4u)
                             ? (unsigned short)0xFFFFu
                             : (unsigned short)(4u * (unsigned)c + sub);
        }
    }
    __syncthreads();

    const int nvalid_l = n_rows - (int)row0;
    const int nvalid = nvalid_l < RPB ? nvalid_l : RPB;

    if (tid < nvalid) {
        // 28 keys = 7 x uint2 (row stride 56B keeps 8B alignment)
        const uint2* kp = reinterpret_cast<const uint2*>(&keys[tid][0]);
        unsigned m = 0xFFFFu;
        #pragma unroll
        for (int j = 0; j < 7; ++j) {
            const uint2 u = kp[j];
            const unsigned a = u.x & 0xFFFFu, b = u.x >> 16;
            const unsigned c2 = u.y & 0xFFFFu, d = u.y >> 16;
            const unsigned ab = a < b ? a : b;
            const unsigned cd = c2 < d ? c2 : d;
            const unsigned e = ab < cd ? ab : cd;
            m = m < e ? m : e;
        }
        const unsigned idx = (m > 107u) ? (unsigned)LZD_NBITS : m;
        float* os = &outs[tid * LZD_NOUT];
        os[0] = (float)((idx >> 6) & 1u);
        os[1] = (float)((idx >> 5) & 1u);
        os[2] = (float)((idx >> 4) & 1u);
        os[3] = (float)((idx >> 3) & 1u);
        os[4] = (float)((idx >> 2) & 1u);
        os[5] = (float)((idx >> 1) & 1u);
        os[6] = (float)(idx & 1u);
    }
    __syncthreads();

    // coalesced writeback: 256*7 contiguous floats per block
    const int limit = nvalid * LZD_NOUT;
    float* ob = out + row0 * LZD_NOUT;
    #pragma unroll
    for (int j = 0; j < LZD_NOUT; ++j) {
        const int k = tid + j * RPB;
        if (k < limit) ob[k] = outs[k];
    }
}

extern "C" void kernel_launch(void* const* d_in, const int* in_sizes, int n_in,
                              void* d_out, int out_size, void* d_ws, size_t ws_size,
                              hipStream_t stream) {
    const float* X = (const float*)d_in[0];
    float* out = (float*)d_out;
    int n_rows = in_sizes[0] / LZD_NBITS;
    int block = 256;
    int grid = (n_rows + RPB - 1) / RPB;
    lzd108_kernel<<<grid, block, 0, stream>>>(X, out, n_rows);
}

// Round 3
// 1028.686 us; speedup vs baseline: 1.0846x; 1.0574x over previous
//
#include <hip/hip_runtime.h>

// VecLeadingZeroDetector108: X [n_rows, 108] float32 bits (exact 0.0/1.0),
// out [n_rows, 7] float32 = binary (MSB-first) index of first set bit, or
// 108 = 1101100b if the row is all zero.
//
// Strategy v4: sector-aligned early-exit, 2 rows per thread.
//  - Each row is read in 64B rounds from its enclosing 64B-aligned sector
//    (off = (108*row) mod 16 leading floats masked out) -> every round is
//    exactly one HBM sector, no straddle waste. Expected ~2.6 sectors/row
//    (p(one)=0.03) ~= 170B/row ~= 340MB total vs 864MB full-stream.
//  - Two adjacent rows per thread = two independent load chains per lane
//    (2x memory-level parallelism, halves exposed round latency) and a
//    55KB-contiguous wave footprint.
//  - Fully unrolled 8 rounds: k==0 low-clip and k>=6 tail-clip/skip-loads
//    are compile-time; last needed uint4 ends exactly at the row boundary
//    (off+108 is a multiple of 4) so no OOB reads ever.
//  - Inputs are exactly 0.0f/1.0f = 0x00000000/0x3F800000, so bit 23 is the
//    value; (w >> (23-j)) & (1<<j) builds the 16-bit first-set mask.
//  - Paired rows write 14 contiguous floats as 7 aligned float2 stores.

#define LZD_NBITS 108
#define LZD_NOUT 7

// 16-bit mask (LSB = earliest float in memory order) from 4 uint4s
#define MASK16(a, b, c, d)                                              \
    ( ((a).x >> 23 & 1u)   | ((a).y >> 22 & 2u)   |                     \
      ((a).z >> 21 & 4u)   | ((a).w >> 20 & 8u)   |                     \
      ((b).x >> 19 & 16u)  | ((b).y >> 18 & 32u)  |                     \
      ((b).z >> 17 & 64u)  | ((b).w >> 16 & 128u) |                     \
      ((c).x >> 15 & 256u) | ((c).y >> 14 & 512u) |                     \
      ((c).z >> 13 & 1024u)| ((c).w >> 12 & 2048u)|                     \
      ((d).x >> 11 & 4096u)| ((d).y >> 10 & 8192u)|                     \
      ((d).z >> 9 & 16384u)| ((d).w >> 8 & 32768u) )

// One 64B round for one row. k is a compile-time constant after unroll.
#define ROW_ROUND(P, off, etot, pos, done)                              \
    if (!(done)) {                                                      \
        const int e_ = (etot) - 16 * k;                                 \
        if (k < 7 || e_ > 0) {                                          \
            uint4 a_, b_, c_, d_;                                       \
            a_ = (P)[4 * k];                                            \
            if (k < 6) {                                                \
                b_ = (P)[4 * k + 1];                                    \
                c_ = (P)[4 * k + 2];                                    \
                d_ = (P)[4 * k + 3];                                    \
            } else if (k == 6) {                                        \
                b_ = (P)[4 * k + 1];                                    \
                c_ = (P)[4 * k + 2];                                    \
                d_ = make_uint4(0u, 0u, 0u, 0u);                        \
                if (e_ > 12) d_ = (P)[4 * k + 3];                       \
            } else {                                                    \
                b_ = make_uint4(0u, 0u, 0u, 0u);                        \
                c_ = make_uint4(0u, 0u, 0u, 0u);                        \
                d_ = make_uint4(0u, 0u, 0u, 0u);                        \
                if (e_ > 4) b_ = (P)[4 * k + 1];                        \
            }                                                           \
            unsigned m_ = MASK16(a_, b_, c_, d_);                       \
            if (k == 0) m_ &= ~((1u << (off)) - 1u);                    \
            if (k >= 6) { if (e_ < 16) m_ &= (1u << e_) - 1u; }         \
            if (m_) {                                                   \
                (pos) = 16 * k + (__ffs(m_) - 1) - (int)(off);          \
                (done) = true;                                          \
            } else if (k >= 6 && e_ <= 16) {                            \
                (done) = true; /* exhausted: pos stays 108 */           \
            }                                                           \
        } else {                                                        \
            (done) = true;                                              \
        }                                                               \
    }

__global__ __launch_bounds__(256) void lzd108_kernel(const float* __restrict__ X,
                                                     float* __restrict__ out,
                                                     int n_rows) {
    const int t = blockIdx.x * blockDim.x + threadIdx.x;
    const int r0 = 2 * t;
    if (r0 >= n_rows) return;
    const bool has1 = (r0 + 1) < n_rows;

    // sector-aligned stream bases; off = floats to skip at the front
    const unsigned off0 = (unsigned)(((unsigned)r0 * 108u) & 15u);
    const unsigned off1 = (unsigned)(((unsigned)(r0 + 1) * 108u) & 15u);
    const uint4* __restrict__ P0 =
        reinterpret_cast<const uint4*>(X + (size_t)r0 * 108u - off0);
    const uint4* __restrict__ P1 =
        reinterpret_cast<const uint4*>(X + (size_t)(r0 + 1) * 108u - off1);
    const int e0t = (int)off0 + LZD_NBITS;  // total floats in row0's stream
    const int e1t = (int)off1 + LZD_NBITS;

    int pos0 = LZD_NBITS, pos1 = LZD_NBITS;
    bool d0 = false, d1 = !has1;

    #pragma unroll
    for (int k = 0; k < 8; ++k) {
        if (d0 && d1) break;
        ROW_ROUND(P0, off0, e0t, pos0, d0)
        ROW_ROUND(P1, off1, e1t, pos1, d1)
    }

    float* o = out + (size_t)r0 * LZD_NOUT;
    if (has1) {
        // 14 contiguous floats, 8B-aligned (56*t bytes): 7x float2 stores
        float v[14];
        #pragma unroll
        for (int j = 0; j < 7; ++j) v[j] = (float)((pos0 >> (6 - j)) & 1);
        #pragma unroll
        for (int j = 0; j < 7; ++j) v[7 + j] = (float)((pos1 >> (6 - j)) & 1);
        float2* o2 = reinterpret_cast<float2*>(o);
        #pragma unroll
        for (int j = 0; j < 7; ++j)
            o2[j] = make_float2(v[2 * j], v[2 * j + 1]);
    } else {
        #pragma unroll
        for (int j = 0; j < 7; ++j) o[j] = (float)((pos0 >> (6 - j)) & 1);
    }
}

extern "C" void kernel_launch(void* const* d_in, const int* in_sizes, int n_in,
                              void* d_out, int out_size, void* d_ws, size_t ws_size,
                              hipStream_t stream) {
    const float* X = (const float*)d_in[0];
    float* out = (float*)d_out;
    int n_rows = in_sizes[0] / LZD_NBITS;
    int block = 256;
    int rows_per_block = 2 * block;
    int grid = (n_rows + rows_per_block - 1) / rows_per_block;
    lzd108_kernel<<<grid, block, 0, stream>>>(X, out, n_rows);
}